// Round 10
// baseline (59.378 us; speedup 1.0000x reference)
//
#include <hip/hip_runtime.h>
#include <hip/hip_fp16.h>
#include <math.h>

#define B 4
#define NBC 128
#define HID 64
#define HC 64
#define WC 64
#define P_TOTAL (HC*WC)
#define HOUT 256
#define WOUT 256
#define NSPLIT 4                // n-quarters
#define NQ (NBC/NSPLIT)         // 32 boundary points per block

typedef __attribute__((ext_vector_type(8)))  short bs8;   // 8 bf16 (4 VGPRs) MFMA A/B frag
typedef __attribute__((ext_vector_type(16))) float fx16;  // 32x32 MFMA C/D frag
typedef __attribute__((ext_vector_type(2)))  float f32x2; // v_pk_*_f32 pair

// Fast exact-gelu: erf via 3-term Abramowitz-Stegun 7.1.25 (|err| <= 2.5e-5).
__device__ __forceinline__ float gelu_fast(float x) {
    float y = fabsf(x) * 0.70710678118654752f;
    float t = __builtin_amdgcn_rcpf(fmaf(0.47047f, y, 1.0f));
    float p = fmaf(t, 0.7478556f, -0.0958798f);
    p = fmaf(t, p, 0.3480242f);
    p = p * t;
    float e = __expf(-y * y);
    float er = fmaf(-p, e, 1.0f);
    float s = copysignf(er, x);
    float hx = 0.5f * x;
    return fmaf(hx, s, hx);
}

// fp32 -> bf16 bits, round-half-up
__device__ __forceinline__ short f2bf(float f) {
    return (short)((__float_as_uint(f) + 0x8000u) >> 16);
}
__device__ __forceinline__ float bf2f(short h) {
    return __uint_as_float(((unsigned)(unsigned short)h) << 16);
}

// ---------------------------------------------------------------------------
// Kernel A: per-(b,n) boundary encoder + fold bfg = bf @ g1w_f + g1b.
// Output PRE-SCALED by 128 (the LUT index scale).
// ---------------------------------------------------------------------------
__global__ void bg_encode(const float* __restrict__ bi,
                          const float* __restrict__ e1w, const float* __restrict__ e1b,
                          const float* __restrict__ e2w, const float* __restrict__ e2b,
                          const float* __restrict__ g1w, const float* __restrict__ g1b,
                          float* __restrict__ bfg) {
    int bn = blockIdx.x;
    int h  = threadIdx.x;
    __shared__ float t1[HID];
    __shared__ float t2[HID];
    float x = bi[bn*3+0], y = bi[bn*3+1], z = bi[bn*3+2];
    float a = x*e1w[0*HID+h] + y*e1w[1*HID+h] + z*e1w[2*HID+h] + e1b[h];
    t1[h] = gelu_fast(a);
    __syncthreads();
    float s = e2b[h];
    #pragma unroll
    for (int k = 0; k < HID; ++k) s += t1[k]*e2w[k*HID+h];
    t2[h] = gelu_fast(s);
    __syncthreads();
    float o = g1b[h];
    #pragma unroll
    for (int k = 0; k < HID; ++k) o += t2[k]*g1w[k*HID+h];
    bfg[bn*HID+h] = o * 128.0f;                  // pre-scaled for LUT indexing
}

// ---------------------------------------------------------------------------
// Kernel B: main contraction. Grid (128 p-tiles, B, 4 n-quarters), block 256.
// Swapped MFMA: D[j][p] = (g2w^T)(h1^T) -> lane's C column = p = lane&31.
// ONE bf16-bits nearest LUT over [-16,16], h=1/128 (4096 u16) serves both
// gelus; index math in f32x2 (v_pk_*). Single MFMA acc chain (hi+lo weights
// interleaved into the same accumulator) to cut VGPR to ~90 -> 5 waves/SIMD;
// the n-split=4 grid (2048 blocks) + 26 KB LDS allow 5+ blocks/CU residency.
// launch_bounds(256,2): (256,4) caused scratch spill (round 4).
// ---------------------------------------------------------------------------
__global__ __launch_bounds__(256, 2) void bg_main(
    const float* __restrict__ bi,
    const float* __restrict__ g1w,     // rows 64,65 = g1w_c ; row 66 = g1w_d
    const float* __restrict__ g2w,     // [64][32]
    const float* __restrict__ g2b,     // [32]
    const float* __restrict__ g3w,     // [32]
    const float* __restrict__ g3b,     // [1]
    const float* __restrict__ dscale,  // [1]
    const float* __restrict__ bfg,     // [B*NBC][HID], pre-scaled x128
    __half* __restrict__ ucp)          // [NSPLIT][B][P_TOTAL] fp16 partials
{
    const int b    = blockIdx.y;
    const int nh   = blockIdx.z;       // n-quarter: 0..3
    const int p0   = blockIdx.x * 32;
    const int tid  = threadIdx.x;
    const int lane = tid & 63;
    const int wid  = tid >> 6;         // 0..3
    const int row  = lane & 31;        // p column of C
    const int half = lane >> 5;        // k/j sub-block

    __shared__ float s_bfg[NQ][HID];           // 8 KB (x128 pre-scaled)
    __shared__ float s_cg[32][66];             // 8.45 KB: cg*128 + 2048, stride 66
    __shared__ unsigned short s_lut16[4096];   // 8 KB: bf16-bits gelu, nearest, [-16,16]
    __shared__ float s_bcx[NQ], s_bcy[NQ];
    __shared__ float s_g1d[HID];               // g1d*128
    __shared__ float s_g2b[32], s_g3w[32];
    __shared__ float s_red[4][32];

    {   // stage this n-quarter's bfg rows (coalesced float4, already scaled)
        const float4* src = (const float4*)(bfg + (b*NBC + nh*NQ)*HID);
        float4* dst = (float4*)(&s_bfg[0][0]);
        #pragma unroll
        for (int i = 0; i < NQ*HID/4/256; ++i)   // 512 float4 / 256 thr = 2
            dst[tid + i*256] = src[tid + i*256];
    }
    if (tid < 64) s_g1d[tid] = g1w[66*HID + tid] * 128.0f;
    if (tid < NQ) {
        int ng = b*NBC + nh*NQ + tid;
        s_bcx[tid] = bi[ng*3+0];
        s_bcy[tid] = bi[ng*3+1];
    }
    if (tid >= 64 && tid < 96)  s_g2b[tid-64] = g2b[tid-64];
    if (tid >= 96 && tid < 128) s_g3w[tid-96] = g3w[tid-96];
    #pragma unroll
    for (int i = 0; i < 8; ++i) {               // cg tile: 2048 items, pre-scaled
        int idx = tid + i*256;
        int pl = idx >> 6, k = idx & 63;
        int pp = p0 + pl;
        float gxx = -1.0f + (2.0f/(WC-1)) * (float)(pp & (WC-1));
        float gyy = -1.0f + (2.0f/(HC-1)) * (float)(pp >> 6);
        s_cg[pl][k] = fmaf(gxx*g1w[64*HID+k] + gyy*g1w[65*HID+k], 128.0f, 2048.0f);
    }
    #pragma unroll
    for (int i = 0; i < 16; ++i) {              // bf16 nearest table (half-shifted nodes)
        int idx = tid + i*256;
        float node = fmaf((float)idx, 0.0078125f, -15.99609375f);  // -16 + (i+0.5)/128
        s_lut16[idx] = (unsigned short)((__float_as_uint(gelu_fast(node)) + 0x8000u) >> 16);
    }

    // g2w^T fragments (A operand), hi+lo bf16 split for accuracy
    bs8 whi[4], wlo[4];
    #pragma unroll
    for (int m = 0; m < 4; ++m) {
        #pragma unroll
        for (int e = 0; e < 8; ++e) {
            int k = m*16 + half*8 + e;
            float w = g2w[k*32 + row];
            short hi = f2bf(w);
            whi[m][e] = hi;
            wlo[m][e] = f2bf(w - bf2f(hi));
        }
    }
    __syncthreads();

    const int p = p0 + row;
    const float gx = -1.0f + (2.0f/(WC-1)) * (float)(p & (WC-1));
    const float gy = -1.0f + (2.0f/(HC-1)) * (float)(p >> 6);
    const float as = fabsf(dscale[0]);
    const float g3bias = g3b[0];

    const f32x2 kZero2 = {0.0f, 0.0f};
    const f32x2 kMax2  = {4095.0f, 4095.0f};
    const f32x2 kScale2 = {128.0f, 128.0f};
    const f32x2 kOff2   = {2048.0f, 2048.0f};

    float accp = 0.0f, wsum = 0.0f;

    for (int ni = 0; ni < NQ/4; ++ni) {         // 8 iters
        const int n = wid*(NQ/4) + ni;          // block-local boundary index
        float dx = s_bcx[n] - gx;
        float dy = s_bcy[n] - gy;
        float dist = sqrtf(fmaf(dx, dx, fmaf(dy, dy, 1e-8f)));
        float wgt = __expf(-as * dist);
        wsum += wgt;
        f32x2 dist2 = {dist, dist};

        fx16 acc;                                // single chain, bias-initialized
        #pragma unroll
        for (int rr = 0; rr < 4; ++rr) {
            float4 bias = *(const float4*)&s_g2b[rr*8 + half*4];
            acc[rr*4+0] = bias.x; acc[rr*4+1] = bias.y;
            acc[rr*4+2] = bias.z; acc[rr*4+3] = bias.w;
        }

        #pragma unroll
        for (int m = 0; m < 4; ++m) {
            const int kb = m*16 + half*8;
            const f32x2* bfg2 = (const f32x2*)&s_bfg[n][kb];
            const f32x2* g1d2 = (const f32x2*)&s_g1d[kb];
            const f32x2* cg2  = (const f32x2*)&s_cg[row][kb];
            bs8 af;                              // B operand: h1^T, col = p
            #pragma unroll
            for (int pr = 0; pr < 4; ++pr) {
                // xi = (bfg + cg + dist*g1d)*128 + 2048, all pre-scaled -> pk ops
                f32x2 xi2 = bfg2[pr] + (dist2 * g1d2[pr] + cg2[pr]);
                xi2 = __builtin_elementwise_min(__builtin_elementwise_max(xi2, kZero2), kMax2);
                af[2*pr+0] = (short)s_lut16[(int)xi2.x];   // ds_read_u16: bf16 bits
                af[2*pr+1] = (short)s_lut16[(int)xi2.y];
            }
            acc = __builtin_amdgcn_mfma_f32_32x32x16_bf16(whi[m], af, acc, 0, 0, 0);
            acc = __builtin_amdgcn_mfma_f32_32x32x16_bf16(wlo[m], af, acc, 0, 0, 0);
        }

        // epilogue: gelu(h2) via the same bf16-nearest LUT, pk index math
        f32x2 s2 = {0.0f, 0.0f};
        #pragma unroll
        for (int rr = 0; rr < 4; ++rr) {
            float4 gw = *(const float4*)&s_g3w[rr*8 + half*4];
            #pragma unroll
            for (int qq = 0; qq < 4; qq += 2) {
                f32x2 h2 = {acc[rr*4+qq], acc[rr*4+qq+1]};
                f32x2 xi2 = h2 * kScale2 + kOff2;
                xi2 = __builtin_elementwise_min(__builtin_elementwise_max(xi2, kZero2), kMax2);
                f32x2 g2v;
                g2v.x = __uint_as_float(((unsigned)s_lut16[(int)xi2.x]) << 16);
                g2v.y = __uint_as_float(((unsigned)s_lut16[(int)xi2.y]) << 16);
                s2 = s2 + g2v * f32x2{((const float*)&gw)[qq], ((const float*)&gw)[qq+1]};
            }
        }
        accp = fmaf(s2.x + s2.y, wgt, accp);
    }

    // combine the two j-halves (lane and lane^32 share the same p)
    float v = accp + __shfl_xor(accp, 32, 64);
    if (half == 0) s_red[wid][row] = fmaf(g3bias, wsum, v);
    __syncthreads();
    if (tid < 32) {
        float sum = s_red[0][tid] + s_red[1][tid] + s_red[2][tid] + s_red[3][tid];
        ucp[(nh*B + b)*P_TOTAL + p0 + tid] = __float2half(sum * (1.0f/NBC));
    }
}

// ---------------------------------------------------------------------------
// Kernel C: combine n-quarter fp16 partials + bilinear align_corners upsample
// ---------------------------------------------------------------------------
__global__ void bg_upsample(const __half* __restrict__ ucp, float* __restrict__ out) {
    int idx = blockIdx.x * 256 + threadIdx.x;
    if (idx >= B*HOUT*WOUT) return;
    int x = idx & (WOUT-1);
    int y = (idx >> 8) & (HOUT-1);
    int b = idx >> 16;
    float fy = (float)y * ((float)(HC-1)/(float)(HOUT-1));
    float fx = (float)x * ((float)(WC-1)/(float)(WOUT-1));
    int y0 = (int)floorf(fy);
    int x0 = (int)floorf(fx);
    int y1 = min(y0+1, HC-1);
    int x1 = min(x0+1, WC-1);
    float wy = fy - (float)y0;
    float wx = fx - (float)x0;
    float v00 = 0.0f, v01 = 0.0f, v10 = 0.0f, v11 = 0.0f;
    #pragma unroll
    for (int q = 0; q < NSPLIT; ++q) {
        const __half* u = ucp + (q*B + b)*P_TOTAL;
        v00 += __half2float(u[y0*WC+x0]);
        v01 += __half2float(u[y0*WC+x1]);
        v10 += __half2float(u[y1*WC+x0]);
        v11 += __half2float(u[y1*WC+x1]);
    }
    float top = v00 + (v01 - v00)*wx;
    float bot = v10 + (v11 - v10)*wx;
    out[idx] = top + (bot - top)*wy;
}

extern "C" void kernel_launch(void* const* d_in, const int* in_sizes, int n_in,
                              void* d_out, int out_size, void* d_ws, size_t ws_size,
                              hipStream_t stream) {
    const float* bi  = (const float*)d_in[0];
    const float* e1w = (const float*)d_in[2];
    const float* e1b = (const float*)d_in[3];
    const float* e2w = (const float*)d_in[4];
    const float* e2b = (const float*)d_in[5];
    const float* g1w = (const float*)d_in[6];
    const float* g1b = (const float*)d_in[7];
    const float* g2w = (const float*)d_in[8];
    const float* g2b = (const float*)d_in[9];
    const float* g3w = (const float*)d_in[10];
    const float* g3b = (const float*)d_in[11];
    const float* ds  = (const float*)d_in[12];
    float* out = (float*)d_out;

    float*  bfg = (float*)d_ws;                 // B*NBC*HID f32 (x128 scaled) = 128 KB
    __half* ucp = (__half*)(bfg + B*NBC*HID);   // NSPLIT*B*P_TOTAL fp16 = 128 KB

    bg_encode<<<dim3(B*NBC), dim3(64), 0, stream>>>(bi, e1w, e1b, e2w, e2b, g1w, g1b, bfg);
    bg_main<<<dim3(P_TOTAL/32, B, NSPLIT), dim3(256), 0, stream>>>(bi, g1w, g2w, g2b, g3w, g3b, ds, bfg, ucp);
    bg_upsample<<<dim3((B*HOUT*WOUT)/256), dim3(256), 0, stream>>>(ucp, out);
}

// Round 11
// 58.019 us; speedup vs baseline: 1.0234x; 1.0234x over previous
//
#include <hip/hip_runtime.h>
#include <math.h>

#define B 4
#define NBC 128
#define HID 64
#define HC 64
#define WC 64
#define P_TOTAL (HC*WC)
#define HOUT 256
#define WOUT 256

typedef __attribute__((ext_vector_type(8)))  short bs8;   // 8 bf16 (4 VGPRs) MFMA A/B frag
typedef __attribute__((ext_vector_type(16))) float fx16;  // 32x32 MFMA C/D frag
typedef __attribute__((ext_vector_type(2)))  float f32x2; // v_pk_*_f32 pair

// Fast exact-gelu: erf via 3-term Abramowitz-Stegun 7.1.25 (|err| <= 2.5e-5).
__device__ __forceinline__ float gelu_fast(float x) {
    float y = fabsf(x) * 0.70710678118654752f;
    float t = __builtin_amdgcn_rcpf(fmaf(0.47047f, y, 1.0f));
    float p = fmaf(t, 0.7478556f, -0.0958798f);
    p = fmaf(t, p, 0.3480242f);
    p = p * t;
    float e = __expf(-y * y);
    float er = fmaf(-p, e, 1.0f);
    float s = copysignf(er, x);
    float hx = 0.5f * x;
    return fmaf(hx, s, hx);
}

// fp32 -> bf16 bits, round-half-up
__device__ __forceinline__ short f2bf(float f) {
    return (short)((__float_as_uint(f) + 0x8000u) >> 16);
}
__device__ __forceinline__ float bf2f(short h) {
    return __uint_as_float(((unsigned)(unsigned short)h) << 16);
}

// ---------------------------------------------------------------------------
// Kernel A0: build the gelu LUT once in global memory (one block).
// 4096 nodes over [-16,16), h=1/128, half-shifted so truncation == nearest;
// values are bf16 bits.
// ---------------------------------------------------------------------------
__global__ void bg_lut(unsigned short* __restrict__ lutg) {
    int i = threadIdx.x;
    #pragma unroll
    for (int r = 0; r < 16; ++r) {
        int idx = i + r*256;
        float node = fmaf((float)idx, 0.0078125f, -15.99609375f);  // -16 + (i+0.5)/128
        lutg[idx] = (unsigned short)((__float_as_uint(gelu_fast(node)) + 0x8000u) >> 16);
    }
}

// ---------------------------------------------------------------------------
// Kernel A: per-(b,n) boundary encoder + fold bfg = bf @ g1w_f + g1b.
// Output PRE-SCALED by 128 (the LUT index scale).
// ---------------------------------------------------------------------------
__global__ void bg_encode(const float* __restrict__ bi,
                          const float* __restrict__ e1w, const float* __restrict__ e1b,
                          const float* __restrict__ e2w, const float* __restrict__ e2b,
                          const float* __restrict__ g1w, const float* __restrict__ g1b,
                          float* __restrict__ bfg) {
    int bn = blockIdx.x;
    int h  = threadIdx.x;
    __shared__ float t1[HID];
    __shared__ float t2[HID];
    float x = bi[bn*3+0], y = bi[bn*3+1], z = bi[bn*3+2];
    float a = x*e1w[0*HID+h] + y*e1w[1*HID+h] + z*e1w[2*HID+h] + e1b[h];
    t1[h] = gelu_fast(a);
    __syncthreads();
    float s = e2b[h];
    #pragma unroll
    for (int k = 0; k < HID; ++k) s += t1[k]*e2w[k*HID+h];
    t2[h] = gelu_fast(s);
    __syncthreads();
    float o = g1b[h];
    #pragma unroll
    for (int k = 0; k < HID; ++k) o += t2[k]*g1w[k*HID+h];
    bfg[bn*HID+h] = o * 128.0f;                  // pre-scaled for LUT indexing
}

// ---------------------------------------------------------------------------
// Kernel B: main contraction. Grid (128 p-tiles, B, 2 n-halves), block 256.
// Round-9 structure (best measured): swapped MFMA D[j][p], two independent
// 4-deep MFMA chains (acch/accl), pk-f32 index math, one bf16-bits nearest
// LUT for both gelus. New in r11: LUT staged from global (no per-block
// rebuild) and dist/wgt software-pipelined one n ahead so the serial
// sqrt/exp head overlaps the previous iteration's body.
// launch_bounds(256,2): (256,4) caused scratch spill (round 4).
// ---------------------------------------------------------------------------
__global__ __launch_bounds__(256, 2) void bg_main(
    const float* __restrict__ bi,
    const float* __restrict__ g1w,     // rows 64,65 = g1w_c ; row 66 = g1w_d
    const float* __restrict__ g2w,     // [64][32]
    const float* __restrict__ g2b,     // [32]
    const float* __restrict__ g3w,     // [32]
    const float* __restrict__ g3b,     // [1]
    const float* __restrict__ dscale,  // [1]
    const float* __restrict__ bfg,     // [B*NBC][HID], pre-scaled x128
    const unsigned short* __restrict__ lutg,  // [4096] bf16-bits gelu
    float* __restrict__ ucp)           // [2][B][P_TOTAL] partials
{
    const int b    = blockIdx.y;
    const int nh   = blockIdx.z;       // n-half: 0 or 1
    const int p0   = blockIdx.x * 32;
    const int tid  = threadIdx.x;
    const int lane = tid & 63;
    const int wid  = tid >> 6;         // 0..3
    const int row  = lane & 31;        // p column of C
    const int half = lane >> 5;        // k/j sub-block

    __shared__ float s_bfg[64][HID];           // 16 KB (x128 pre-scaled)
    __shared__ float s_cg[32][66];             // 8.45 KB: cg*128 + 2048, stride 66
    __shared__ unsigned short s_lut16[4096];   // 8 KB, staged from global
    __shared__ float s_bcx[64], s_bcy[64];
    __shared__ float s_g1d[HID];               // g1d*128
    __shared__ float s_g2b[32], s_g3w[32];
    __shared__ float s_red[4][32];

    {   // stage this n-half's bfg rows (coalesced float4, already scaled)
        const float4* src = (const float4*)(bfg + (b*NBC + nh*64)*HID);
        float4* dst = (float4*)(&s_bfg[0][0]);
        #pragma unroll
        for (int i = 0; i < 4; ++i)
            dst[tid + i*256] = src[tid + i*256];
    }
    {   // stage the LUT (8 KB): 512 uint4, 2 per thread
        const uint4* src = (const uint4*)lutg;
        uint4* dst = (uint4*)s_lut16;
        dst[tid]       = src[tid];
        dst[tid + 256] = src[tid + 256];
    }
    if (tid < 64) {
        int ng = b*NBC + nh*64 + tid;
        s_bcx[tid] = bi[ng*3+0];
        s_bcy[tid] = bi[ng*3+1];
        s_g1d[tid] = g1w[66*HID + tid] * 128.0f;
    }
    if (tid >= 64 && tid < 96)  s_g2b[tid-64] = g2b[tid-64];
    if (tid >= 96 && tid < 128) s_g3w[tid-96] = g3w[tid-96];
    #pragma unroll
    for (int i = 0; i < 8; ++i) {               // cg tile: 2048 items, pre-scaled
        int idx = tid + i*256;
        int pl = idx >> 6, k = idx & 63;
        int pp = p0 + pl;
        float gxx = -1.0f + (2.0f/(WC-1)) * (float)(pp & (WC-1));
        float gyy = -1.0f + (2.0f/(HC-1)) * (float)(pp >> 6);
        s_cg[pl][k] = fmaf(gxx*g1w[64*HID+k] + gyy*g1w[65*HID+k], 128.0f, 2048.0f);
    }

    // g2w^T fragments (A operand), hi+lo bf16 split for accuracy
    bs8 whi[4], wlo[4];
    #pragma unroll
    for (int m = 0; m < 4; ++m) {
        #pragma unroll
        for (int e = 0; e < 8; ++e) {
            int k = m*16 + half*8 + e;
            float w = g2w[k*32 + row];
            short hi = f2bf(w);
            whi[m][e] = hi;
            wlo[m][e] = f2bf(w - bf2f(hi));
        }
    }
    __syncthreads();

    const int p = p0 + row;
    const float gx = -1.0f + (2.0f/(WC-1)) * (float)(p & (WC-1));
    const float gy = -1.0f + (2.0f/(HC-1)) * (float)(p >> 6);
    const float as = fabsf(dscale[0]);
    const float g3bias = g3b[0];

    const f32x2 kZero2 = {0.0f, 0.0f};
    const f32x2 kMax2  = {4095.0f, 4095.0f};
    const f32x2 kScale2 = {128.0f, 128.0f};
    const f32x2 kOff2   = {2048.0f, 2048.0f};

    float accp = 0.0f, wsum = 0.0f;

    // software-pipelined dist/wgt (serial sqrt/exp head overlaps prev body)
    float dx0 = s_bcx[wid*16] - gx;
    float dy0 = s_bcy[wid*16] - gy;
    float dist = sqrtf(fmaf(dx0, dx0, fmaf(dy0, dy0, 1e-8f)));
    float wgt  = __expf(-as * dist);

    for (int ni = 0; ni < 16; ++ni) {
        float distN = 0.0f, wgtN = 0.0f;
        if (ni < 15) {                           // prefetch next n's head
            int n1 = wid*16 + ni + 1;
            float dx = s_bcx[n1] - gx;
            float dy = s_bcy[n1] - gy;
            distN = sqrtf(fmaf(dx, dx, fmaf(dy, dy, 1e-8f)));
            wgtN  = __expf(-as * distN);
        }
        const int n = wid*16 + ni;              // block-local boundary index
        wsum += wgt;
        f32x2 dist2 = {dist, dist};

        fx16 acch, accl;                         // two independent MFMA chains
        #pragma unroll
        for (int rr = 0; rr < 4; ++rr) {
            float4 bias = *(const float4*)&s_g2b[rr*8 + half*4];
            acch[rr*4+0] = bias.x; acch[rr*4+1] = bias.y;
            acch[rr*4+2] = bias.z; acch[rr*4+3] = bias.w;
            accl[rr*4+0] = 0.0f;  accl[rr*4+1] = 0.0f;
            accl[rr*4+2] = 0.0f;  accl[rr*4+3] = 0.0f;
        }

        #pragma unroll
        for (int m = 0; m < 4; ++m) {
            const int kb = m*16 + half*8;
            const f32x2* bfg2 = (const f32x2*)&s_bfg[n][kb];
            const f32x2* g1d2 = (const f32x2*)&s_g1d[kb];
            const f32x2* cg2  = (const f32x2*)&s_cg[row][kb];
            bs8 af;                              // B operand: h1^T, col = p
            #pragma unroll
            for (int pr = 0; pr < 4; ++pr) {
                // xi = (bfg + cg + dist*g1d)*128 + 2048, all pre-scaled -> pk ops
                f32x2 xi2 = bfg2[pr] + (dist2 * g1d2[pr] + cg2[pr]);
                xi2 = __builtin_elementwise_min(__builtin_elementwise_max(xi2, kZero2), kMax2);
                af[2*pr+0] = (short)s_lut16[(int)xi2.x];   // ds_read_u16: bf16 bits
                af[2*pr+1] = (short)s_lut16[(int)xi2.y];
            }
            acch = __builtin_amdgcn_mfma_f32_32x32x16_bf16(whi[m], af, acch, 0, 0, 0);
            accl = __builtin_amdgcn_mfma_f32_32x32x16_bf16(wlo[m], af, accl, 0, 0, 0);
        }

        // epilogue: gelu(h2) via the same bf16-nearest LUT, pk index math
        f32x2 s2 = {0.0f, 0.0f};
        #pragma unroll
        for (int rr = 0; rr < 4; ++rr) {
            float4 gw = *(const float4*)&s_g3w[rr*8 + half*4];
            #pragma unroll
            for (int qq = 0; qq < 4; qq += 2) {
                f32x2 h2 = f32x2{acch[rr*4+qq], acch[rr*4+qq+1]}
                         + f32x2{accl[rr*4+qq], accl[rr*4+qq+1]};
                f32x2 xi2 = h2 * kScale2 + kOff2;
                xi2 = __builtin_elementwise_min(__builtin_elementwise_max(xi2, kZero2), kMax2);
                f32x2 g2v;
                g2v.x = __uint_as_float(((unsigned)s_lut16[(int)xi2.x]) << 16);
                g2v.y = __uint_as_float(((unsigned)s_lut16[(int)xi2.y]) << 16);
                s2 = s2 + g2v * f32x2{((const float*)&gw)[qq], ((const float*)&gw)[qq+1]};
            }
        }
        accp = fmaf(s2.x + s2.y, wgt, accp);
        dist = distN; wgt = wgtN;
    }

    // combine the two j-halves (lane and lane^32 share the same p)
    float v = accp + __shfl_xor(accp, 32, 64);
    if (half == 0) s_red[wid][row] = fmaf(g3bias, wsum, v);
    __syncthreads();
    if (tid < 32) {
        float sum = s_red[0][tid] + s_red[1][tid] + s_red[2][tid] + s_red[3][tid];
        ucp[(nh*B + b)*P_TOTAL + p0 + tid] = sum * (1.0f/NBC);
    }
}

// ---------------------------------------------------------------------------
// Kernel C: combine n-half partials + bilinear align_corners upsample
// ---------------------------------------------------------------------------
__global__ void bg_upsample(const float* __restrict__ ucp, float* __restrict__ out) {
    int idx = blockIdx.x * 256 + threadIdx.x;
    if (idx >= B*HOUT*WOUT) return;
    int x = idx & (WOUT-1);
    int y = (idx >> 8) & (HOUT-1);
    int b = idx >> 16;
    float fy = (float)y * ((float)(HC-1)/(float)(HOUT-1));
    float fx = (float)x * ((float)(WC-1)/(float)(WOUT-1));
    int y0 = (int)floorf(fy);
    int x0 = (int)floorf(fx);
    int y1 = min(y0+1, HC-1);
    int x1 = min(x0+1, WC-1);
    float wy = fy - (float)y0;
    float wx = fx - (float)x0;
    const float* u0 = ucp + b*P_TOTAL;
    const float* u1 = ucp + (B + b)*P_TOTAL;
    float v00 = u0[y0*WC+x0] + u1[y0*WC+x0];
    float v01 = u0[y0*WC+x1] + u1[y0*WC+x1];
    float v10 = u0[y1*WC+x0] + u1[y1*WC+x0];
    float v11 = u0[y1*WC+x1] + u1[y1*WC+x1];
    float top = v00 + (v01 - v00)*wx;
    float bot = v10 + (v11 - v10)*wx;
    out[idx] = top + (bot - top)*wy;
}

extern "C" void kernel_launch(void* const* d_in, const int* in_sizes, int n_in,
                              void* d_out, int out_size, void* d_ws, size_t ws_size,
                              hipStream_t stream) {
    const float* bi  = (const float*)d_in[0];
    const float* e1w = (const float*)d_in[2];
    const float* e1b = (const float*)d_in[3];
    const float* e2w = (const float*)d_in[4];
    const float* e2b = (const float*)d_in[5];
    const float* g1w = (const float*)d_in[6];
    const float* g1b = (const float*)d_in[7];
    const float* g2w = (const float*)d_in[8];
    const float* g2b = (const float*)d_in[9];
    const float* g3w = (const float*)d_in[10];
    const float* g3b = (const float*)d_in[11];
    const float* ds  = (const float*)d_in[12];
    float* out = (float*)d_out;

    float* bfg = (float*)d_ws;                         // 128 KB (x128 scaled)
    float* ucp = bfg + B*NBC*HID;                      // 128 KB partials
    unsigned short* lutg = (unsigned short*)(ucp + 2*B*P_TOTAL);  // 8 KB

    bg_lut<<<dim3(1), dim3(256), 0, stream>>>(lutg);
    bg_encode<<<dim3(B*NBC), dim3(64), 0, stream>>>(bi, e1w, e1b, e2w, e2b, g1w, g1b, bfg);
    bg_main<<<dim3(P_TOTAL/32, B, 2), dim3(256), 0, stream>>>(bi, g1w, g2w, g2b, g3w, g3b, ds, bfg, lutg, ucp);
    bg_upsample<<<dim3((B*HOUT*WOUT)/256), dim3(256), 0, stream>>>(ucp, out);
}